// Round 8
// baseline (447.872 us; speedup 1.0000x reference)
//
#include <hip/hip_runtime.h>
#include <hip/hip_fp16.h>

// CapsNet dynamic routing, B=256 N=2048 C=10 D_IN=8 D_OUT=16, ROUTING_ITERS=3.
// R8: cut uhat (160 MB fp16, L3-resident) passes 5 -> 2(+L2):
//   caps_s0    : iter-0 s from u,W directly (GEMV, no uhat)     ~20 us
//   build_uhat : unchanged R7 (proven byte-exact)               ~55 us
//   caps_cs    : fused agreement+softmax+s-accum per iter (x2)  ~35 us
//                phase-B re-reads the block's 20 KB i-slice L2-hot.
//   reduceA/squash : unchanged.
// Codegen discipline (R4-R6 lesson): small bodies, no big register arrays,
// all accumulators in LDS (single-owner cells), outer loops dynamic.
// ws: uhat 160 MB + s_part 21 MB + vT0/vsumT.

#define B_SZ  256
#define N_SZ  2048
#define C_SZ  10
#define DIN   8
#define DOUT  16
#define JO    (C_SZ*DOUT)   // 160
#define IC    16            // i's per chunk
#define NCH   (N_SZ/IC)     // 128
#define WROW  (JO*DIN)      // 1280 floats per i

__device__ __forceinline__ void softmax10(float* a) {
    float m = a[0];
#pragma unroll
    for (int j = 1; j < C_SZ; ++j) m = fmaxf(m, a[j]);
    float s = 0.f;
#pragma unroll
    for (int j = 0; j < C_SZ; ++j) { a[j] = __expf(a[j] - m); s += a[j]; }
    float inv = 1.f / s;
#pragma unroll
    for (int j = 0; j < C_SZ; ++j) a[j] *= inv;
}

// iter-0: s_part[ch][jo][b] = sum_{i in chunk} dot(W[i][jo],u[b][i]) (c=0.1 via pre_scale)
__global__ __launch_bounds__(256)
void caps_s0(const float* __restrict__ u, const float* __restrict__ W,
             float* __restrict__ s_part)
{
    __shared__ __align__(16) float Wl[WROW];     // 5 KB: W[i]
    __shared__ float s_acc[JO*64];               // 40 KB: [jo][bl], single-owner cells
    const int tid  = threadIdx.x;
    const int bl   = tid & 63;
    const int unit = tid >> 6;                   // wave id: owns jo0..jo0+39
    const int ch   = blockIdx.x >> 2;
    const int bg   = blockIdx.x & 3;
    const int b    = bg*64 + bl;
    const int jo0  = unit*40;

    for (int k = tid; k < JO*64; k += 256) s_acc[k] = 0.f;

    for (int il = 0; il < IC; ++il) {
        const int i = ch*IC + il;
        __syncthreads();                         // Wl readers done (and s_acc init at il=0)
        for (int k = tid; k < WROW/4; k += 256)  // 320 float4, coalesced (proven construct)
            ((float4*)Wl)[k] = ((const float4*)(W + (size_t)i*WROW))[k];
        __syncthreads();
        const float* up = u + ((size_t)b*N_SZ + i)*DIN;   // 32 B/lane (L2 absorbs, proven)
        const float4 ua = ((const float4*)up)[0];
        const float4 ub = ((const float4*)up)[1];
        for (int k = 0; k < 40; ++k) {
            const int jo = jo0 + k;              // wave-uniform -> LDS broadcast reads
            const float4 w0 = ((const float4*)(Wl + jo*DIN))[0];
            const float4 w1 = ((const float4*)(Wl + jo*DIN))[1];
            float uh = w0.x*ua.x;
            uh = fmaf(w0.y,ua.y,uh); uh = fmaf(w0.z,ua.z,uh); uh = fmaf(w0.w,ua.w,uh);
            uh = fmaf(w1.x,ub.x,uh); uh = fmaf(w1.y,ub.y,uh);
            uh = fmaf(w1.z,ub.z,uh); uh = fmaf(w1.w,ub.w,uh);
            s_acc[jo*64 + bl] += uh;             // lanes->banks 2-way, free; no atomics
        }
    }
    __syncthreads();
    float* outp = s_part + (size_t)ch*(JO*B_SZ) + bg*64;
    for (int k = tid; k < JO*64; k += 256)       // coalesced 256 B runs
        outp[(k>>6)*B_SZ + (k&63)] = s_acc[k];
}

// uhat[i][jo][b] = dot(W[i][jo][:], u[b][i][:])  (fp32 math, fp16 store) — R7-proven
__global__ __launch_bounds__(256)
void build_uhat(const float* __restrict__ u, const float* __restrict__ W,
                __half* __restrict__ uhat)
{
    __shared__ __align__(16) float Wl[WROW];       // 5 KB: W[i]
    const int i = blockIdx.x;
    const int b = threadIdx.x;
    for (int k = b; k < WROW/4; k += 256)
        ((float4*)Wl)[k] = ((const float4*)(W + (size_t)i*WROW))[k];
    __syncthreads();
    const float* up = u + ((size_t)b*N_SZ + i)*DIN;
    const float4 ua = ((const float4*)up)[0];
    const float4 ub = ((const float4*)up)[1];
    __half* dst = uhat + (size_t)i*JO*B_SZ + b;
#pragma unroll 2
    for (int jo = 0; jo < JO; ++jo) {
        const float4 w0 = ((const float4*)(Wl + jo*DIN))[0];
        const float4 w1 = ((const float4*)(Wl + jo*DIN))[1];
        float uh = w0.x*ua.x;
        uh = fmaf(w0.y, ua.y, uh); uh = fmaf(w0.z, ua.z, uh); uh = fmaf(w0.w, ua.w, uh);
        uh = fmaf(w1.x, ub.x, uh); uh = fmaf(w1.y, ub.y, uh);
        uh = fmaf(w1.z, ub.z, uh); uh = fmaf(w1.w, ub.w, uh);
        dst[(size_t)jo*B_SZ] = __float2half(uh);
    }
}

// Fused per-iteration: agreement -> softmax -> s accumulation.
// Per i: phase A reads the i-slice (cold); phase B re-reads it L2-hot.
__global__ __launch_bounds__(256)
void caps_cs(const __half* __restrict__ uhat, const float* __restrict__ vT,
             float* __restrict__ s_part)
{
    __shared__ float s_acc[JO*64];               // 40 KB: [jo][bl]
    __shared__ float al[C_SZ*64];                // 2.5 KB: agreement logits [j][bl]
    __shared__ float cl[C_SZ*64];                // 2.5 KB: softmax coeffs  [j][bl]
    const int tid  = threadIdx.x;
    const int bl   = tid & 63;
    const int unit = tid >> 6;
    const int ch   = blockIdx.x >> 2;
    const int bg   = blockIdx.x & 3;
    const int b    = bg*64 + bl;
    const int jo0  = unit*40;

    for (int k = tid; k < JO*64; k += 256) s_acc[k] = 0.f;
    __syncthreads();

    for (int il = 0; il < IC; ++il) {
        const int i = ch*IC + il;
        const __half* up = uhat + (size_t)i*(JO*B_SZ) + b;
        // phase A: agreement logits; unit's j-set {unit, unit+4, unit+8}
        for (int jj = 0; jj < 3; ++jj) {
            const int j = unit + 4*jj;           // wave-uniform branch
            if (j < C_SZ) {
                float acc = 0.f;
#pragma unroll
                for (int o = 0; o < DOUT; ++o) {
                    const int jo = j*DOUT + o;
                    acc = fmaf(__half2float(up[(size_t)jo*B_SZ]),   // 128 B coalesced
                               vT[jo*B_SZ + b], acc);               // L2/L1-hot
                }
                al[j*64 + bl] = acc;
            }
        }
        __syncthreads();
        // softmax: wave 0, one b per lane (R1/R7-proven static a[10] construct)
        if (tid < 64) {
            float a[C_SZ];
#pragma unroll
            for (int j = 0; j < C_SZ; ++j) a[j] = al[j*64 + tid];
            softmax10(a);
#pragma unroll
            for (int j = 0; j < C_SZ; ++j) cl[j*64 + tid] = a[j];
        }
        __syncthreads();
        // phase B: s[jo][bl] += c[jo/16][bl] * uh (i-slice re-read, L2-hot)
        for (int k = 0; k < 40; ++k) {
            const int jo = jo0 + k;
            s_acc[jo*64 + bl] = fmaf(cl[(jo>>4)*64 + bl],
                                     __half2float(up[(size_t)jo*B_SZ]),
                                     s_acc[jo*64 + bl]);
        }
        // no end barrier needed: next il's post-A sync orders cl reuse.
    }
    __syncthreads();
    float* outp = s_part + (size_t)ch*(JO*B_SZ) + bg*64;
    for (int k = tid; k < JO*64; k += 256)       // coalesced 256 B runs
        outp[(k>>6)*B_SZ + (k&63)] = s_acc[k];
}

// Sum the 128 chunk partials; overwrite chunk-0 slice as s_sum[jo][b].
__global__ __launch_bounds__(256)
void caps_reduceA(float* __restrict__ s_part, float pre_scale)
{
    const int idx = blockIdx.x*256 + threadIdx.x;      // < 40960
    float s = 0.f;
    for (int c = 0; c < NCH; ++c) s += s_part[(size_t)c*(JO*B_SZ) + idx];
    s_part[idx] = s * pre_scale;
}

// squash per (b,j); write vT_out = v (+ vT_prev), or final outputs.
__global__ __launch_bounds__(256)
void caps_squash(const float* __restrict__ s_sum, const float* __restrict__ vT_prev,
                 float* __restrict__ vT_out, float* __restrict__ out_v,
                 float* __restrict__ out_logit)
{
    const int t = blockIdx.x*256 + threadIdx.x;        // < 2560
    const int b = t / C_SZ, j = t % C_SZ;
    float sv[DOUT]; float n2 = 0.f;
#pragma unroll
    for (int o = 0; o < DOUT; ++o) {
        const float x = s_sum[(j*DOUT + o)*B_SZ + b];
        sv[o] = x; n2 = fmaf(x, x, n2);
    }
    const float norm  = sqrtf(n2);
    const float nc    = fmaxf(norm, 1e-7f);
    const float scale = 1.f - 1.f/(1.f + nc*nc);       // matches reference
    const float inv   = scale / nc;
    if (vT_out) {
#pragma unroll
        for (int o = 0; o < DOUT; ++o) {
            const float v = sv[o]*inv;
            const float p = vT_prev ? vT_prev[(j*DOUT + o)*B_SZ + b] : 0.f;
            vT_out[(j*DOUT + o)*B_SZ + b] = v + p;     // iter-1 writes v0+v1 directly
        }
    }
    if (out_v) {
        float q = 0.f;
#pragma unroll
        for (int o = 0; o < DOUT; ++o) {
            const float v = sv[o]*inv;
            out_v[(size_t)b*JO + j*DOUT + o] = v;      // [256,10,16]
            q = fmaf(v, v, q);
        }
        out_logit[t] = sqrtf(q);                       // [256,10]
    }
}

extern "C" void kernel_launch(void* const* d_in, const int* in_sizes, int n_in,
                              void* d_out, int out_size, void* d_ws, size_t ws_size,
                              hipStream_t stream)
{
    const float* u = (const float*)d_in[0];   // [256,2048,8]
    const float* W = (const float*)d_in[1];   // [2048,10,16,8]
    float* out_v     = (float*)d_out;         // [256,10,16]
    float* out_logit = out_v + B_SZ*JO;       // [256,10]

    __half* uhat  = (__half*)d_ws;                                    // 167,772,160 B
    float* s_part = (float*)((char*)d_ws + (size_t)N_SZ*JO*B_SZ*2);   // 20,971,520 B
    float* vT0    = s_part + (size_t)NCH*JO*B_SZ;                     // 163,840 B
    float* vsumT  = vT0 + JO*B_SZ;                                    // 163,840 B

    dim3 blk(256), gcs(NCH*4), gbuild(N_SZ), gred(JO*B_SZ/256), gsq(B_SZ*C_SZ/256);

    // iter 0: s from u,W directly (uniform c folded into pre_scale 0.1)
    caps_s0<<<gcs, blk, 0, stream>>>(u, W, s_part);
    caps_reduceA<<<gred, blk, 0, stream>>>(s_part, 0.1f);
    caps_squash<<<gsq, blk, 0, stream>>>(s_part, nullptr, vT0, nullptr, nullptr);
    // materialize uhat fp16 (needed by iters 1,2)
    build_uhat<<<gbuild, blk, 0, stream>>>(u, W, uhat);
    // iter 1: c = softmax(uh.v0)
    caps_cs<<<gcs, blk, 0, stream>>>(uhat, vT0, s_part);
    caps_reduceA<<<gred, blk, 0, stream>>>(s_part, 1.0f);
    caps_squash<<<gsq, blk, 0, stream>>>(s_part, vT0, vsumT, nullptr, nullptr);
    // iter 2: c = softmax(uh.(v0+v1)); final squash -> outputs
    caps_cs<<<gcs, blk, 0, stream>>>(uhat, vsumT, s_part);
    caps_reduceA<<<gred, blk, 0, stream>>>(s_part, 1.0f);
    caps_squash<<<gsq, blk, 0, stream>>>(s_part, nullptr, nullptr, out_v, out_logit);
}

// Round 9
// 425.507 us; speedup vs baseline: 1.0526x; 1.0526x over previous
//
#include <hip/hip_runtime.h>
#include <hip/hip_fp16.h>

// CapsNet dynamic routing, B=256 N=2048 C=10 D_IN=8 D_OUT=16, ROUTING_ITERS=3.
// R9: R8's fusion was right (2nd uhat read cache-hot) but 32 barriers/block
// serialized it (VALUBusy 7.6%). caps_cs now has 3 block-wide phases and only
// 2 barriers; all loads half2/float2; s accumulated in registers (exclusive
// (jo,b-pair) cells -> no LDS s_acc, no atomics). caps_s0 (120 us, barrier-
// bound) replaced by reduce_uhat: iter-0 s = 0.1 * sum_i uhat (pure stream).
// Codegen discipline (R4-R6): small bodies, static small arrays only.
// ws: uhat 160 MB + s_part 21 MB + vT0/vsumT.

#define B_SZ  256
#define N_SZ  2048
#define C_SZ  10
#define DIN   8
#define DOUT  16
#define JO    (C_SZ*DOUT)   // 160
#define IC    16            // i's per chunk
#define NCH   (N_SZ/IC)     // 128
#define WROW  (JO*DIN)      // 1280 floats per i

__device__ __forceinline__ void softmax10(float* a) {
    float m = a[0];
#pragma unroll
    for (int j = 1; j < C_SZ; ++j) m = fmaxf(m, a[j]);
    float s = 0.f;
#pragma unroll
    for (int j = 0; j < C_SZ; ++j) { a[j] = __expf(a[j] - m); s += a[j]; }
    float inv = 1.f / s;
#pragma unroll
    for (int j = 0; j < C_SZ; ++j) a[j] *= inv;
}

// uhat[i][jo][b] = dot(W[i][jo][:], u[b][i][:])  (fp32 math, fp16 store) — R7-proven
__global__ __launch_bounds__(256)
void build_uhat(const float* __restrict__ u, const float* __restrict__ W,
                __half* __restrict__ uhat)
{
    __shared__ __align__(16) float Wl[WROW];       // 5 KB: W[i]
    const int i = blockIdx.x;
    const int b = threadIdx.x;
    for (int k = b; k < WROW/4; k += 256)
        ((float4*)Wl)[k] = ((const float4*)(W + (size_t)i*WROW))[k];
    __syncthreads();
    const float* up = u + ((size_t)b*N_SZ + i)*DIN;
    const float4 ua = ((const float4*)up)[0];
    const float4 ub = ((const float4*)up)[1];
    __half* dst = uhat + (size_t)i*JO*B_SZ + b;
#pragma unroll 2
    for (int jo = 0; jo < JO; ++jo) {
        const float4 w0 = ((const float4*)(Wl + jo*DIN))[0];
        const float4 w1 = ((const float4*)(Wl + jo*DIN))[1];
        float uh = w0.x*ua.x;
        uh = fmaf(w0.y, ua.y, uh); uh = fmaf(w0.z, ua.z, uh); uh = fmaf(w0.w, ua.w, uh);
        uh = fmaf(w1.x, ub.x, uh); uh = fmaf(w1.y, ub.y, uh);
        uh = fmaf(w1.z, ub.z, uh); uh = fmaf(w1.w, ub.w, uh);
        dst[(size_t)jo*B_SZ] = __float2half(uh);
    }
}

// iter-0 partials: s_part[g][jo][b] = sum over g's 128 i's of uhat. Pure stream.
__global__ __launch_bounds__(256)
void reduce_uhat(const __half* __restrict__ uhat, float* __restrict__ s_part)
{
    const int g    = blockIdx.y;                        // 0..15
    const int idx2 = blockIdx.x*256 + threadIdx.x;      // (jo,bp) cell, < 20480
    const __half2* src = (const __half2*)uhat + (size_t)g*128*(JO*B_SZ/2) + idx2;
    float2 acc{0.f, 0.f};
    for (int ii = 0; ii < 128; ++ii) {                  // coalesced 256 B runs
        const float2 x = __half22float2(src[(size_t)ii*(JO*B_SZ/2)]);
        acc.x += x.x; acc.y += x.y;
    }
    ((float2*)s_part)[(size_t)g*(JO*B_SZ/2) + idx2] = acc;
}

// Fused per-iteration kernel: 3 phases, 2 barriers.
//  A: agreement logits for all (il,j)   -> cl LDS    (320 indep half2 loads/thread)
//  B: softmax all (il,b) in-place in cl (4 tasks/thread, static a[10])
//  C: s[jo][b-pair] accumulated in registers, written straight to s_part.
__global__ __launch_bounds__(256)
void caps_cs(const __half* __restrict__ uhat, const float* __restrict__ vT,
             float* __restrict__ s_part)
{
    __shared__ float2 cl[IC*C_SZ*32];    // 40960 B: [il][j][bp] (logits then coeffs)
    const int t    = threadIdx.x;
    const int bp   = t & 31;             // b-pair within 64-b group
    const int unit = t >> 5;             // 0..7
    const int ch   = blockIdx.x >> 2;
    const int bg   = blockIdx.x & 3;
    const int bO   = bg*64 + 2*bp;       // global b of .x component

    // ---- phase A: unit handles il = unit*2 + il2 ----
    for (int il2 = 0; il2 < 2; ++il2) {
        const int il = unit*2 + il2;
        const __half2* up = (const __half2*)(uhat + (size_t)(ch*IC + il)*(JO*B_SZ) + bO);
        for (int j = 0; j < C_SZ; ++j) {
            float2 acc{0.f, 0.f};
#pragma unroll
            for (int o = 0; o < DOUT; ++o) {
                const int jo = j*DOUT + o;
                const float2 uh = __half22float2(up[(size_t)jo*(B_SZ/2)]);
                const float2 vv = *(const float2*)(vT + jo*B_SZ + bO);
                acc.x = fmaf(uh.x, vv.x, acc.x);
                acc.y = fmaf(uh.y, vv.y, acc.y);
            }
            cl[(il*C_SZ + j)*32 + bp] = acc;
        }
    }
    __syncthreads();
    // ---- phase B: softmax, 1024 (il,b) tasks, 4/thread, in-place (exclusive cells) ----
    for (int q = 0; q < 4; ++q) {
        const int task = q*256 + t;
        const int il   = task >> 6;      // 0..15
        const int bloc = task & 63;      // local b; float index (il*10+j)*64 + bloc
        float* base = (float*)cl + (size_t)il*(C_SZ*64) + bloc;
        float a[C_SZ];                   // static-indexed (R1/R7-proven)
#pragma unroll
        for (int j = 0; j < C_SZ; ++j) a[j] = base[j*64];
        softmax10(a);
#pragma unroll
        for (int j = 0; j < C_SZ; ++j) base[j*64] = a[j];
    }
    __syncthreads();
    // ---- phase C: cell (jo, bp) exclusive -> register accumulate, direct store ----
    float* outp = s_part + (size_t)ch*(JO*B_SZ) + bO;
    for (int k = 0; k < 20; ++k) {
        const int jo = unit*20 + k;
        const int j  = jo >> 4;
        const __half2* up = (const __half2*)(uhat + (size_t)(ch*IC)*(JO*B_SZ)
                                             + (size_t)jo*B_SZ + bO);
        float2 acc{0.f, 0.f};
#pragma unroll
        for (int il = 0; il < IC; ++il) {
            const float2 uh = __half22float2(up[(size_t)il*(JO*B_SZ/2)]);  // L2/L3-hot
            const float2 c  = cl[(il*C_SZ + j)*32 + bp];
            acc.x = fmaf(c.x, uh.x, acc.x);
            acc.y = fmaf(c.y, uh.y, acc.y);
        }
        *(float2*)(outp + (size_t)jo*B_SZ) = acc;    // coalesced, exact 20 MB total
    }
}

// Sum `count` chunk partials (stride JO*B); overwrite slice 0 as s_sum[jo][b].
__global__ __launch_bounds__(256)
void caps_reduceA(float* __restrict__ s_part, int count, float pre_scale)
{
    const int idx = blockIdx.x*256 + threadIdx.x;      // < 40960
    float s = 0.f;
    for (int c = 0; c < count; ++c) s += s_part[(size_t)c*(JO*B_SZ) + idx];
    s_part[idx] = s * pre_scale;
}

// squash per (b,j); write vT_out = v (+ vT_prev), or final outputs.
__global__ __launch_bounds__(256)
void caps_squash(const float* __restrict__ s_sum, const float* __restrict__ vT_prev,
                 float* __restrict__ vT_out, float* __restrict__ out_v,
                 float* __restrict__ out_logit)
{
    const int t = blockIdx.x*256 + threadIdx.x;        // < 2560
    const int b = t / C_SZ, j = t % C_SZ;
    float sv[DOUT]; float n2 = 0.f;
#pragma unroll
    for (int o = 0; o < DOUT; ++o) {
        const float x = s_sum[(j*DOUT + o)*B_SZ + b];
        sv[o] = x; n2 = fmaf(x, x, n2);
    }
    const float norm  = sqrtf(n2);
    const float nc    = fmaxf(norm, 1e-7f);
    const float scale = 1.f - 1.f/(1.f + nc*nc);       // matches reference
    const float inv   = scale / nc;
    if (vT_out) {
#pragma unroll
        for (int o = 0; o < DOUT; ++o) {
            const float v = sv[o]*inv;
            const float p = vT_prev ? vT_prev[(j*DOUT + o)*B_SZ + b] : 0.f;
            vT_out[(j*DOUT + o)*B_SZ + b] = v + p;     // iter-1 writes v0+v1 directly
        }
    }
    if (out_v) {
        float q = 0.f;
#pragma unroll
        for (int o = 0; o < DOUT; ++o) {
            const float v = sv[o]*inv;
            out_v[(size_t)b*JO + j*DOUT + o] = v;      // [256,10,16]
            q = fmaf(v, v, q);
        }
        out_logit[t] = sqrtf(q);                       // [256,10]
    }
}

extern "C" void kernel_launch(void* const* d_in, const int* in_sizes, int n_in,
                              void* d_out, int out_size, void* d_ws, size_t ws_size,
                              hipStream_t stream)
{
    const float* u = (const float*)d_in[0];   // [256,2048,8]
    const float* W = (const float*)d_in[1];   // [2048,10,16,8]
    float* out_v     = (float*)d_out;         // [256,10,16]
    float* out_logit = out_v + B_SZ*JO;       // [256,10]

    __half* uhat  = (__half*)d_ws;                                    // 167,772,160 B
    float* s_part = (float*)((char*)d_ws + (size_t)N_SZ*JO*B_SZ*2);   // 20,971,520 B
    float* vT0    = s_part + (size_t)NCH*JO*B_SZ;                     // 163,840 B
    float* vsumT  = vT0 + JO*B_SZ;                                    // 163,840 B

    dim3 blk(256), gbuild(N_SZ), gcs(NCH*4), gru(80, 16),
         gred(JO*B_SZ/256), gsq(B_SZ*C_SZ/256);

    // materialize uhat fp16
    build_uhat<<<gbuild, blk, 0, stream>>>(u, W, uhat);
    // iter 0: s = 0.1 * sum_i uhat  (uniform softmax folded into pre_scale)
    reduce_uhat<<<gru, blk, 0, stream>>>(uhat, s_part);
    caps_reduceA<<<gred, blk, 0, stream>>>(s_part, 16, 0.1f);
    caps_squash<<<gsq, blk, 0, stream>>>(s_part, nullptr, vT0, nullptr, nullptr);
    // iter 1: c = softmax(uh.v0)
    caps_cs<<<gcs, blk, 0, stream>>>(uhat, vT0, s_part);
    caps_reduceA<<<gred, blk, 0, stream>>>(s_part, NCH, 1.0f);
    caps_squash<<<gsq, blk, 0, stream>>>(s_part, vT0, vsumT, nullptr, nullptr);
    // iter 2: c = softmax(uh.(v0+v1)); final squash -> outputs
    caps_cs<<<gcs, blk, 0, stream>>>(uhat, vsumT, s_part);
    caps_reduceA<<<gred, blk, 0, stream>>>(s_part, NCH, 1.0f);
    caps_squash<<<gsq, blk, 0, stream>>>(s_part, nullptr, nullptr, out_v, out_logit);
}

// Round 10
// 401.810 us; speedup vs baseline: 1.1146x; 1.0590x over previous
//
#include <hip/hip_runtime.h>
#include <hip/hip_fp16.h>

// CapsNet dynamic routing, B=256 N=2048 C=10 D_IN=8 D_OUT=16, ROUTING_ITERS=3.
// R10: R9's 3-phase fused caps_cs was latency-bound at 21% occupancy (grid 512
// = 2 blocks/CU, 4 B/lane loads). Fixes: IC=8 (grid 1024 -> 4 blocks/CU,
// cl 20 KB), 8 B/lane half4 loads (float2 raw + 2x half2 unpack), float4
// vT/cl/s_part accesses. reduce_uhat widened the same way. Structure and ws
// layout otherwise identical to the proven R9 (WRITE byte-exact, no phantom).

#define B_SZ  256
#define N_SZ  2048
#define C_SZ  10
#define DIN   8
#define DOUT  16
#define JO    (C_SZ*DOUT)   // 160
#define IC    8             // i's per chunk
#define NCH   (N_SZ/IC)     // 256
#define WROW  (JO*DIN)      // 1280 floats per i

__device__ __forceinline__ void softmax10(float* a) {
    float m = a[0];
#pragma unroll
    for (int j = 1; j < C_SZ; ++j) m = fmaxf(m, a[j]);
    float s = 0.f;
#pragma unroll
    for (int j = 0; j < C_SZ; ++j) { a[j] = __expf(a[j] - m); s += a[j]; }
    float inv = 1.f / s;
#pragma unroll
    for (int j = 0; j < C_SZ; ++j) a[j] *= inv;
}

// uhat[i][jo][b] = dot(W[i][jo][:], u[b][i][:])  (fp32 math, fp16 store) — R7-proven
__global__ __launch_bounds__(256)
void build_uhat(const float* __restrict__ u, const float* __restrict__ W,
                __half* __restrict__ uhat)
{
    __shared__ __align__(16) float Wl[WROW];       // 5 KB: W[i]
    const int i = blockIdx.x;
    const int b = threadIdx.x;
    for (int k = b; k < WROW/4; k += 256)
        ((float4*)Wl)[k] = ((const float4*)(W + (size_t)i*WROW))[k];
    __syncthreads();
    const float* up = u + ((size_t)b*N_SZ + i)*DIN;
    const float4 ua = ((const float4*)up)[0];
    const float4 ub = ((const float4*)up)[1];
    __half* dst = uhat + (size_t)i*JO*B_SZ + b;
#pragma unroll 2
    for (int jo = 0; jo < JO; ++jo) {
        const float4 w0 = ((const float4*)(Wl + jo*DIN))[0];
        const float4 w1 = ((const float4*)(Wl + jo*DIN))[1];
        float uh = w0.x*ua.x;
        uh = fmaf(w0.y, ua.y, uh); uh = fmaf(w0.z, ua.z, uh); uh = fmaf(w0.w, ua.w, uh);
        uh = fmaf(w1.x, ub.x, uh); uh = fmaf(w1.y, ub.y, uh);
        uh = fmaf(w1.z, ub.z, uh); uh = fmaf(w1.w, ub.w, uh);
        dst[(size_t)jo*B_SZ] = __float2half(uh);
    }
}

// iter-0 partials: s_part[g][jo][b] = sum over g's 32 i's of uhat. Pure stream, 8 B/lane.
__global__ __launch_bounds__(256)
void reduce_uhat(const __half* __restrict__ uhat, float* __restrict__ s_part)
{
    const int g    = blockIdx.y;                        // 0..63
    const int cell = blockIdx.x*256 + threadIdx.x;      // 4-half cell, < 10240
    const char* src = (const char*)uhat + (size_t)g*32*(JO*B_SZ*2) + (size_t)cell*8;
    float4 acc{0.f,0.f,0.f,0.f};
    for (int ii = 0; ii < 32; ++ii) {                   // coalesced 512 B/wave runs
        const float2 raw = *(const float2*)(src + (size_t)ii*(JO*B_SZ*2));
        const __half2 h0 = *(const __half2*)&raw.x;
        const __half2 h1 = *(const __half2*)&raw.y;
        const float2 x0 = __half22float2(h0);
        const float2 x1 = __half22float2(h1);
        acc.x += x0.x; acc.y += x0.y; acc.z += x1.x; acc.w += x1.y;
    }
    ((float4*)s_part)[(size_t)g*(JO*B_SZ/4) + cell] = acc;
}

// Fused per-iteration kernel: 3 phases, 2 barriers (R9-proven structure).
//  A: agreement logits for all (il,j) -> cl LDS   (80 indep 8B loads/thread)
//  B: softmax all (il,b), 2 tasks/thread, static a[10]
//  C: s[jo][4b] register-accumulated, direct float4 store to s_part.
__global__ __launch_bounds__(256)
void caps_cs(const __half* __restrict__ uhat, const float* __restrict__ vT,
             float* __restrict__ s_part)
{
    __shared__ __align__(16) float cl[IC*C_SZ*64];   // 20480 B: [il][j][bl]
    const int t    = threadIdx.x;
    const int bq   = t & 15;          // 4-b quad within the 64-b group
    const int unit = t >> 4;          // 0..15
    const int ch   = blockIdx.x >> 2;
    const int bg   = blockIdx.x & 3;
    const int b0   = bg*64 + 4*bq;

    // ---- phase A: unit -> (il = unit>>1, j = (unit&1)*5 + jj) ----
    {
        const int il = unit >> 1;
        const int j0 = (unit & 1)*5;
        const char* up = (const char*)(uhat + (size_t)(ch*IC + il)*(JO*B_SZ) + b0);
        for (int jj = 0; jj < 5; ++jj) {
            const int j = j0 + jj;
            float4 acc{0.f,0.f,0.f,0.f};
#pragma unroll
            for (int o = 0; o < DOUT; ++o) {
                const int jo = j*DOUT + o;
                const float2 raw = *(const float2*)(up + (size_t)jo*(B_SZ*2));
                const __half2 h0 = *(const __half2*)&raw.x;
                const __half2 h1 = *(const __half2*)&raw.y;
                const float2 x0 = __half22float2(h0);
                const float2 x1 = __half22float2(h1);
                const float4 vv = *(const float4*)(vT + jo*B_SZ + b0);
                acc.x = fmaf(x0.x, vv.x, acc.x);
                acc.y = fmaf(x0.y, vv.y, acc.y);
                acc.z = fmaf(x1.x, vv.z, acc.z);
                acc.w = fmaf(x1.y, vv.w, acc.w);
            }
            ((float4*)cl)[(il*C_SZ + j)*16 + bq] = acc;
        }
    }
    __syncthreads();
    // ---- phase B: 512 (il,bloc) softmax tasks, 2/thread, in-place ----
    for (int q = 0; q < 2; ++q) {
        const int task = q*256 + t;
        const int il   = task >> 6;
        const int bloc = task & 63;
        float* base = cl + (size_t)il*(C_SZ*64) + bloc;
        float a[C_SZ];                   // static-indexed (R1/R7/R9-proven)
#pragma unroll
        for (int j = 0; j < C_SZ; ++j) a[j] = base[j*64];
        softmax10(a);
#pragma unroll
        for (int j = 0; j < C_SZ; ++j) base[j*64] = a[j];
    }
    __syncthreads();
    // ---- phase C: unit owns jo = unit*10+k; exclusive (jo, 4b) cells ----
    const char* upC = (const char*)(uhat + (size_t)(ch*IC)*(JO*B_SZ) + b0);
    float* outp = s_part + (size_t)ch*(JO*B_SZ) + b0;
    for (int k = 0; k < 10; ++k) {
        const int jo = unit*10 + k;
        const int j  = jo >> 4;
        const char* up = upC + (size_t)jo*(B_SZ*2);
        float4 acc{0.f,0.f,0.f,0.f};
#pragma unroll
        for (int il = 0; il < IC; ++il) {
            const float2 raw = *(const float2*)(up + (size_t)il*(JO*B_SZ*2));  // L2/L3-hot
            const __half2 h0 = *(const __half2*)&raw.x;
            const __half2 h1 = *(const __half2*)&raw.y;
            const float2 x0 = __half22float2(h0);
            const float2 x1 = __half22float2(h1);
            const float4 c = ((const float4*)cl)[(il*C_SZ + j)*16 + bq];
            acc.x = fmaf(c.x, x0.x, acc.x);
            acc.y = fmaf(c.y, x0.y, acc.y);
            acc.z = fmaf(c.z, x1.x, acc.z);
            acc.w = fmaf(c.w, x1.y, acc.w);
        }
        *(float4*)(outp + (size_t)jo*B_SZ) = acc;    // coalesced float4 runs
    }
}

// Sum `count` chunk partials (stride JO*B); overwrite slice 0 as s_sum[jo][b].
__global__ __launch_bounds__(256)
void caps_reduceA(float* __restrict__ s_part, int count, float pre_scale)
{
    const int idx = blockIdx.x*256 + threadIdx.x;      // < 40960
    float s = 0.f;
    for (int c = 0; c < count; ++c) s += s_part[(size_t)c*(JO*B_SZ) + idx];
    s_part[idx] = s * pre_scale;
}

// squash per (b,j); write vT_out = v (+ vT_prev), or final outputs.
__global__ __launch_bounds__(256)
void caps_squash(const float* __restrict__ s_sum, const float* __restrict__ vT_prev,
                 float* __restrict__ vT_out, float* __restrict__ out_v,
                 float* __restrict__ out_logit)
{
    const int t = blockIdx.x*256 + threadIdx.x;        // < 2560
    const int b = t / C_SZ, j = t % C_SZ;
    float sv[DOUT]; float n2 = 0.f;
#pragma unroll
    for (int o = 0; o < DOUT; ++o) {
        const float x = s_sum[(j*DOUT + o)*B_SZ + b];
        sv[o] = x; n2 = fmaf(x, x, n2);
    }
    const float norm  = sqrtf(n2);
    const float nc    = fmaxf(norm, 1e-7f);
    const float scale = 1.f - 1.f/(1.f + nc*nc);       // matches reference
    const float inv   = scale / nc;
    if (vT_out) {
#pragma unroll
        for (int o = 0; o < DOUT; ++o) {
            const float v = sv[o]*inv;
            const float p = vT_prev ? vT_prev[(j*DOUT + o)*B_SZ + b] : 0.f;
            vT_out[(j*DOUT + o)*B_SZ + b] = v + p;     // iter-1 writes v0+v1 directly
        }
    }
    if (out_v) {
        float q = 0.f;
#pragma unroll
        for (int o = 0; o < DOUT; ++o) {
            const float v = sv[o]*inv;
            out_v[(size_t)b*JO + j*DOUT + o] = v;      // [256,10,16]
            q = fmaf(v, v, q);
        }
        out_logit[t] = sqrtf(q);                       // [256,10]
    }
}

extern "C" void kernel_launch(void* const* d_in, const int* in_sizes, int n_in,
                              void* d_out, int out_size, void* d_ws, size_t ws_size,
                              hipStream_t stream)
{
    const float* u = (const float*)d_in[0];   // [256,2048,8]
    const float* W = (const float*)d_in[1];   // [2048,10,16,8]
    float* out_v     = (float*)d_out;         // [256,10,16]
    float* out_logit = out_v + B_SZ*JO;       // [256,10]

    __half* uhat  = (__half*)d_ws;                                    // 167,772,160 B
    float* s_part = (float*)((char*)d_ws + (size_t)N_SZ*JO*B_SZ*2);   // 41,943,040 B (256 slices)
    float* vT0    = s_part + (size_t)NCH*JO*B_SZ;                     // 163,840 B
    float* vsumT  = vT0 + JO*B_SZ;                                    // 163,840 B

    dim3 blk(256), gbuild(N_SZ), gcs(NCH*4), gru(40, 64),
         gred(JO*B_SZ/256), gsq(B_SZ*C_SZ/256);

    // materialize uhat fp16
    build_uhat<<<gbuild, blk, 0, stream>>>(u, W, uhat);
    // iter 0: s = 0.1 * sum_i uhat  (uniform softmax folded into pre_scale)
    reduce_uhat<<<gru, blk, 0, stream>>>(uhat, s_part);
    caps_reduceA<<<gred, blk, 0, stream>>>(s_part, 64, 0.1f);
    caps_squash<<<gsq, blk, 0, stream>>>(s_part, nullptr, vT0, nullptr, nullptr);
    // iter 1: c = softmax(uh.v0)
    caps_cs<<<gcs, blk, 0, stream>>>(uhat, vT0, s_part);
    caps_reduceA<<<gred, blk, 0, stream>>>(s_part, NCH, 1.0f);
    caps_squash<<<gsq, blk, 0, stream>>>(s_part, vT0, vsumT, nullptr, nullptr);
    // iter 2: c = softmax(uh.(v0+v1)); final squash -> outputs
    caps_cs<<<gcs, blk, 0, stream>>>(uhat, vsumT, s_part);
    caps_reduceA<<<gred, blk, 0, stream>>>(s_part, NCH, 1.0f);
    caps_squash<<<gsq, blk, 0, stream>>>(s_part, nullptr, nullptr, out_v, out_logit);
}